// Round 15
// baseline (108.957 us; speedup 1.0000x reference)
//
#include <hip/hip_runtime.h>
#include <math.h>

// ---------------- problem constants ----------------
#define NB        512
#define ND        32
#define NCOND     30
#define NS        21                  // NB_STEPS+1 quadrature nodes
#define NBD       (NB*ND)             // 16384
#define NROWS     (NBD*NS)            // 344064 MLP evaluations
#define MBLK      64                  // rows per block
#define NBLOCKS   (NROWS/MBLK)        // 5376

// packed-weight element counts (ushort)
#define W0P_ELEMS (1*16*64*8)         // 8192
#define W1P_ELEMS (8*16*64*8)         // 65536
#define W3P_ELEMS (8*64*8)            // 4096  (zero-padded W3 as A-fragments)
#define WP_TOTAL  (W0P_ELEMS + 2*W1P_ELEMS + W3P_ELEMS)  // 143360

typedef __bf16 bf8 __attribute__((ext_vector_type(8)));
typedef float  fx4 __attribute__((ext_vector_type(4)));
typedef unsigned short us8 __attribute__((ext_vector_type(8)));

__device__ __forceinline__ unsigned short f2bf(float f) {
  unsigned int u = __float_as_uint(f);
  u += 0x7FFFu + ((u >> 16) & 1u);        // round-to-nearest-even
  return (unsigned short)(u >> 16);
}

// ---------------- kernel 1: pack weights to bf16 MFMA fragment order ----------
__global__ void prep_pack(const float* __restrict__ W0,
                          const float* __restrict__ W1,
                          const float* __restrict__ W2,
                          const float* __restrict__ W3,
                          unsigned short* __restrict__ wp) {
  int t = blockIdx.x * blockDim.x + threadIdx.x;   // one thread = one 8-elem frag
  if (t >= WP_TOTAL / 8) return;
  int base = t * 8;
  us8 out;
  if (base >= W0P_ELEMS + 2 * W1P_ELEMS) {         // W3 region
    int rem  = base - (W0P_ELEMS + 2 * W1P_ELEMS);
    int lane = (rem >> 3) & 63;
    int ktl  = rem >> 9;
    int k0   = ktl * 32 + (lane >> 4) * 8;
#pragma unroll
    for (int i = 0; i < 8; ++i)
      out[i] = ((lane & 15) == 0) ? f2bf(W3[k0 + i]) : (unsigned short)0;
  } else {
    const float* W; int rem, K;
    if (base < W0P_ELEMS)                  { W = W0; rem = base;                 K = 31;  }
    else if (base < W0P_ELEMS + W1P_ELEMS) { W = W1; rem = base - W0P_ELEMS;     K = 256; }
    else                                   { W = W2; rem = base - W0P_ELEMS - W1P_ELEMS; K = 256; }
    int lane = (rem >> 3) & 63;
    int ct   = (rem >> 9) & 15;
    int ktl  =  rem >> 13;
    int j  = ct * 16 + (lane & 15);
    int k0 = ktl * 32 + (lane >> 4) * 8;
#pragma unroll
    for (int i = 0; i < 8; ++i) {
      int k = k0 + i;
      out[i] = (k < K) ? f2bf(W[k * 256 + j]) : (unsigned short)0;
    }
  }
  *reinterpret_cast<us8*>(wp + base) = out;
}

// ---------------- fused MLP kernel ----------------
// R13 structure, arg2 = 3. Cross-round occupancy regression (R3 vs R6 A/B:
// same LDS/threads, arg2 4 vs 2 -> 12.4 vs 6.3 waves/CU) shows launch_bounds
// arg2 on this toolchain BOTH caps VGPR at 256/arg2 AND caps residency at
// ~arg2 waves/SIMD. R13 compiled to 76 VGPR <= 85 = 256/3, so (512,3) keeps
// it spill-free while unlocking 3 waves/SIMD (12 waves/CU) residency.
// 8 waves/block (512 thr), block = 64 rows. Wave = 4 row-tiles x 2 col-tiles
// (cgrp = wv, 32 neurons): acc[4][2] = 32 VGPR. Weight fragments read exactly
// once per block. Act dbuf aa/ab + weight dbuf wa/wb. Ping-pong ldsA/ldsB
// (1 barrier/layer), bias-in-accumulator, setprio retained.

#define ACC_BIAS(BIAS)                                                           \
  {                                                                              \
    float4 bq0 = *reinterpret_cast<const float4*>((BIAS) + (cgrp * 2 + 0) * 16 + khalf * 4); \
    float4 bq1 = *reinterpret_cast<const float4*>((BIAS) + (cgrp * 2 + 1) * 16 + khalf * 4); \
    _Pragma("unroll")                                                            \
    for (int rt = 0; rt < 4; ++rt) {                                             \
      acc[rt][0] = fx4{bq0.x, bq0.y, bq0.z, bq0.w};                              \
      acc[rt][1] = fx4{bq1.x, bq1.y, bq1.z, bq1.w};                              \
    }                                                                            \
  }

#define LOADW2(S0,S1, WB, KT)                                                    \
  S0 = *reinterpret_cast<const bf8*>((WB) + (((KT) * 16 + cgrp * 2 + 0) * 64 + lane) * 8); \
  S1 = *reinterpret_cast<const bf8*>((WB) + (((KT) * 16 + cgrp * 2 + 1) * 64 + lane) * 8);

#define AOFF(M, KT) (((unsigned)((M) * 512 + (KT) * 64 + khalf * 16)) ^ ((unsigned)(((M) & 15) << 4)))

#define ALOAD(A0,A1,A2,A3, SRC, KT)                                              \
  A0 = *reinterpret_cast<const bf8*>((SRC) + AOFF( 0 + colb, KT));               \
  A1 = *reinterpret_cast<const bf8*>((SRC) + AOFF(16 + colb, KT));               \
  A2 = *reinterpret_cast<const bf8*>((SRC) + AOFF(32 + colb, KT));               \
  A3 = *reinterpret_cast<const bf8*>((SRC) + AOFF(48 + colb, KT));

#define KMFMA(W0_,W1_, A0,A1,A2,A3)                                              \
  __builtin_amdgcn_s_setprio(1);                                                 \
  acc[0][0] = __builtin_amdgcn_mfma_f32_16x16x32_bf16(W0_, A0, acc[0][0], 0, 0, 0); \
  acc[0][1] = __builtin_amdgcn_mfma_f32_16x16x32_bf16(W1_, A0, acc[0][1], 0, 0, 0); \
  acc[1][0] = __builtin_amdgcn_mfma_f32_16x16x32_bf16(W0_, A1, acc[1][0], 0, 0, 0); \
  acc[1][1] = __builtin_amdgcn_mfma_f32_16x16x32_bf16(W1_, A1, acc[1][1], 0, 0, 0); \
  acc[2][0] = __builtin_amdgcn_mfma_f32_16x16x32_bf16(W0_, A2, acc[2][0], 0, 0, 0); \
  acc[2][1] = __builtin_amdgcn_mfma_f32_16x16x32_bf16(W1_, A2, acc[2][1], 0, 0, 0); \
  acc[3][0] = __builtin_amdgcn_mfma_f32_16x16x32_bf16(W0_, A3, acc[3][0], 0, 0, 0); \
  acc[3][1] = __builtin_amdgcn_mfma_f32_16x16x32_bf16(W1_, A3, acc[3][1], 0, 0, 0); \
  __builtin_amdgcn_s_setprio(0);

// 8 K-steps: act dbuf aa/ab (prefetch kt+1 before kt's MFMAs), weight dbuf
// wa/wb (reload kt+2 after use). Tail prefetches next layer's kt0/kt1 weights.
#define DENSE_PIPE(SRC, WB, NWB)                                                 \
  ALOAD(aa0,aa1,aa2,aa3, SRC, 0)                                                 \
  ALOAD(ab0,ab1,ab2,ab3, SRC, 1) KMFMA(wa0,wa1, aa0,aa1,aa2,aa3) LOADW2(wa0,wa1, WB, 2) \
  ALOAD(aa0,aa1,aa2,aa3, SRC, 2) KMFMA(wb0,wb1, ab0,ab1,ab2,ab3) LOADW2(wb0,wb1, WB, 3) \
  ALOAD(ab0,ab1,ab2,ab3, SRC, 3) KMFMA(wa0,wa1, aa0,aa1,aa2,aa3) LOADW2(wa0,wa1, WB, 4) \
  ALOAD(aa0,aa1,aa2,aa3, SRC, 4) KMFMA(wb0,wb1, ab0,ab1,ab2,ab3) LOADW2(wb0,wb1, WB, 5) \
  ALOAD(ab0,ab1,ab2,ab3, SRC, 5) KMFMA(wa0,wa1, aa0,aa1,aa2,aa3) LOADW2(wa0,wa1, WB, 6) \
  ALOAD(aa0,aa1,aa2,aa3, SRC, 6) KMFMA(wb0,wb1, ab0,ab1,ab2,ab3) LOADW2(wb0,wb1, WB, 7) \
  ALOAD(ab0,ab1,ab2,ab3, SRC, 7) KMFMA(wa0,wa1, aa0,aa1,aa2,aa3) LOADW2(wa0,wa1, NWB, 0) \
                                 KMFMA(wb0,wb1, ab0,ab1,ab2,ab3) LOADW2(wb0,wb1, NWB, 1)

#define DENSE_LAST(SRC, WB)                                                      \
  ALOAD(aa0,aa1,aa2,aa3, SRC, 0)                                                 \
  ALOAD(ab0,ab1,ab2,ab3, SRC, 1) KMFMA(wa0,wa1, aa0,aa1,aa2,aa3) LOADW2(wa0,wa1, WB, 2) \
  ALOAD(aa0,aa1,aa2,aa3, SRC, 2) KMFMA(wb0,wb1, ab0,ab1,ab2,ab3) LOADW2(wb0,wb1, WB, 3) \
  ALOAD(ab0,ab1,ab2,ab3, SRC, 3) KMFMA(wa0,wa1, aa0,aa1,aa2,aa3) LOADW2(wa0,wa1, WB, 4) \
  ALOAD(aa0,aa1,aa2,aa3, SRC, 4) KMFMA(wb0,wb1, ab0,ab1,ab2,ab3) LOADW2(wb0,wb1, WB, 5) \
  ALOAD(ab0,ab1,ab2,ab3, SRC, 5) KMFMA(wa0,wa1, aa0,aa1,aa2,aa3) LOADW2(wa0,wa1, WB, 6) \
  ALOAD(aa0,aa1,aa2,aa3, SRC, 6) KMFMA(wb0,wb1, ab0,ab1,ab2,ab3) LOADW2(wb0,wb1, WB, 7) \
  ALOAD(ab0,ab1,ab2,ab3, SRC, 7) KMFMA(wa0,wa1, aa0,aa1,aa2,aa3)                 \
                                 KMFMA(wb0,wb1, ab0,ab1,ab2,ab3)

// ReLU + bf16-pack + ds_write_b64 store of acc into DST (bias already in acc)
#define ACT_STORE(DST)                                                           \
  {                                                                              \
    _Pragma("unroll")                                                            \
    for (int rt = 0; rt < 4; ++rt) {                                             \
      int m = rt * 16 + colb;                                                    \
      unsigned int sbase = (unsigned int)(m * 512);                              \
      unsigned int swz   = (unsigned int)((m & 15) << 4);                        \
      _Pragma("unroll")                                                          \
      for (int ct = 0; ct < 2; ++ct) {                                           \
        int n0 = (cgrp * 2 + ct) * 16 + khalf * 4;                               \
        float v0 = fmaxf(acc[rt][ct][0], 0.f);                                   \
        float v1 = fmaxf(acc[rt][ct][1], 0.f);                                   \
        float v2 = fmaxf(acc[rt][ct][2], 0.f);                                   \
        float v3 = fmaxf(acc[rt][ct][3], 0.f);                                   \
        unsigned int p0, p1;                                                     \
        asm("v_cvt_pk_bf16_f32 %0, %1, %2" : "=v"(p0) : "v"(v0), "v"(v1));       \
        asm("v_cvt_pk_bf16_f32 %0, %1, %2" : "=v"(p1) : "v"(v2), "v"(v3));       \
        uint2 pk; pk.x = p0; pk.y = p1;                                          \
        *reinterpret_cast<uint2*>((DST) + ((sbase + (unsigned int)(n0 * 2)) ^ swz)) = pk; \
      }                                                                          \
    }                                                                            \
  }

__global__ __launch_bounds__(512, 3)
void mlp_kernel(const float* __restrict__ x, const float* __restrict__ h,
                const float* __restrict__ b0, const float* __restrict__ b1,
                const float* __restrict__ b2, const float* __restrict__ b3,
                const unsigned short* __restrict__ wp,
                float* __restrict__ fbuf) {
  __shared__ __align__(16) unsigned char ldsA[64 * 512];     // 32 KiB
  __shared__ __align__(16) unsigned char ldsB[64 * 512];     // 32 KiB
  unsigned char* ldsIn = ldsB;         // layer-0 input overlays ldsB[0:4K]

  int tid  = threadIdx.x;
  int wv   = tid >> 6;
  int lane = tid & 63;
  int cgrp = wv;                 // 0..7 : 32-neuron group; wave owns all 64 rows
  int colb  = lane & 15;
  int khalf = lane >> 4;
  int R0 = blockIdx.x * MBLK;

  const unsigned short* wb1p = wp + W0P_ELEMS;
  const unsigned short* wb2p = wp + W0P_ELEMS + W1P_ELEMS;
  const unsigned short* w3p  = wp + W0P_ELEMS + 2 * W1P_ELEMS;

  bf8 wa0, wa1, wb0, wb1;
  bf8 aa0, aa1, aa2, aa3, ab0, ab1, ab2, ab3;
  // layer-0 weights (single K-step) into slot A, issued before input staging
  LOADW2(wa0, wa1, wp, 0);

  // ---- stage layer-0 input [64 rows][32 bf16] into ldsIn (= ldsB[0:4K]) ----
  if (tid < 256) {
    int r = tid >> 2;                   // 0..63
    int q = tid & 3;                    // 8-col chunk
    int gr = R0 + r;
    unsigned int bd = (unsigned int)gr / NS;
    int s = gr - (int)bd * NS;
    float xv = x[bd];
    float node = xv * (cosf((float)s * 0.15707963267948966f) + 1.0f) * 0.5f;
    const float* hrow = h + bd * NCOND;
    us8 au;
#pragma unroll
    for (int i = 0; i < 8; ++i) {
      int c = q * 8 + i;
      float v;
      if (c == 0)       v = node;
      else if (c <= 30) v = hrow[c - 1];
      else              v = 0.0f;
      au[i] = f2bf(v);
    }
    unsigned int off = (unsigned int)(r * 64 + q * 16) ^ (unsigned int)((r & 3) << 4);
    *reinterpret_cast<us8*>(ldsIn + off) = au;
  }
  __syncthreads();

  fx4 acc[4][2];

  // ======== layer 0: K=32, read ldsIn(B), store ldsA — no mid barrier ========
  {
    ACC_BIAS(b0);
#pragma unroll
    for (int rt = 0; rt < 4; ++rt) {
      int m = rt * 16 + colb;
      unsigned int off = (unsigned int)(m * 64 + khalf * 16) ^ (unsigned int)((m & 3) << 4);
      bf8 a = *reinterpret_cast<const bf8*>(ldsIn + off);
      acc[rt][0] = __builtin_amdgcn_mfma_f32_16x16x32_bf16(wa0, a, acc[rt][0], 0, 0, 0);
      acc[rt][1] = __builtin_amdgcn_mfma_f32_16x16x32_bf16(wa1, a, acc[rt][1], 0, 0, 0);
    }
    // prefetch layer-1 kt0/kt1 weights; loads straddle the store + barrier
    LOADW2(wa0, wa1, wb1p, 0);
    LOADW2(wb0, wb1, wb1p, 1);
    ACT_STORE(ldsA);                    // different buffer: no barrier needed
  }
  __syncthreads();

  // ======== layer 1: read ldsA, store ldsB (one barrier after stores) ========
  ACC_BIAS(b1);
  DENSE_PIPE(ldsA, wb1p, wb2p);          // tail prefetches layer-2 kt0/kt1
  ACT_STORE(ldsB);
  __syncthreads();

  // ======== layer 2: read ldsB, store ldsA ========
  ACC_BIAS(b2);
  DENSE_LAST(ldsB, wb2p);
  ACT_STORE(ldsA);
  __syncthreads();

  // ======== layer 3: 256 -> 1 via MFMA, waves 0-3, rows wv*16..wv*16+15 ======
  if (wv < 4) {
    fx4 a3 = fx4{0.f, 0.f, 0.f, 0.f};
    int m = wv * 16 + colb;
    unsigned int abase = (unsigned int)(m * 512 + khalf * 16);
    unsigned int aswz  = (unsigned int)((m & 15) << 4);
#pragma unroll
    for (int kt = 0; kt < 8; ++kt) {
      bf8 w3f = *reinterpret_cast<const bf8*>(w3p + (kt * 64 + lane) * 8);
      bf8 a = *reinterpret_cast<const bf8*>(ldsA + ((abase + (unsigned)(kt * 64)) ^ aswz));
      a3 = __builtin_amdgcn_mfma_f32_16x16x32_bf16(w3f, a, a3, 0, 0, 0);
    }
    if (lane < 16) {
      float y = a3[0] + b3[0];
      float f = (y > 0.f) ? (y + 1.f) : expf(y);   // elu(y)+1
      fbuf[R0 + wv * 16 + lane] = f;
    }
  }
}

// ---------------- kernel 3: Clenshaw-Curtis reduction -> z, jac ----------------
__global__ void reduce_kernel(const float* __restrict__ x, const float* __restrict__ h,
                              const float* __restrict__ fbuf, float* __restrict__ out) {
  __shared__ float ccw[NS];
  int tid = threadIdx.x;
  if (tid < NS) {
    double acc = 0.0;
#pragma unroll
    for (int i = 0; i <= 20; i += 2) {
      double wi = (i == 0) ? 1.0 : 2.0 / (1.0 - (double)(i * i));
      acc += cos((double)(i * tid) * 3.141592653589793 / 20.0) * wi;
    }
    double edge = (tid == 0 || tid == 20) ? 0.5 : 1.0;
    ccw[tid] = (float)(acc * 0.1 * edge);          // * 2/nb_steps * edge
  }
  __syncthreads();
  int t = blockIdx.x * blockDim.x + tid;
  if (t >= NBD) return;
  const float* fb = fbuf + t * NS;
  float acc = 0.f;
#pragma unroll
  for (int i = 0; i < NS; ++i) acc += fb[i] * ccw[i];
  float z = acc * x[t] * 0.5f + h[t * NCOND];
  out[t] = z;                     // z_est + h[:,:,0]
  out[NBD + t] = fb[0];           // jac = f at node s=0 (steps[0]==1 -> input == [x,h])
}

// ---------------- launcher ----------------
extern "C" void kernel_launch(void* const* d_in, const int* in_sizes, int n_in,
                              void* d_out, int out_size, void* d_ws, size_t ws_size,
                              hipStream_t stream) {
  (void)in_sizes; (void)n_in; (void)out_size; (void)ws_size;
  const float* x  = (const float*)d_in[0];
  const float* h  = (const float*)d_in[1];
  const float* W0 = (const float*)d_in[2];
  const float* b0 = (const float*)d_in[3];
  const float* W1 = (const float*)d_in[4];
  const float* b1 = (const float*)d_in[5];
  const float* W2 = (const float*)d_in[6];
  const float* b2 = (const float*)d_in[7];
  const float* W3 = (const float*)d_in[8];
  const float* b3 = (const float*)d_in[9];

  unsigned short* wp = (unsigned short*)d_ws;
  float* fbuf = (float*)((char*)d_ws + WP_TOTAL * sizeof(unsigned short));
  float* out  = (float*)d_out;

  prep_pack<<<(WP_TOTAL / 8 + 255) / 256, 256, 0, stream>>>(W0, W1, W2, W3, wp);
  mlp_kernel<<<NBLOCKS, 512, 0, stream>>>(x, h, b0, b1, b2, b3, wp, fbuf);
  reduce_kernel<<<(NBD + 255) / 256, 256, 0, stream>>>(x, h, fbuf, out);
}

// Round 16
// 101.044 us; speedup vs baseline: 1.0783x; 1.0783x over previous
//
#include <hip/hip_runtime.h>
#include <math.h>

// ---------------- problem constants ----------------
#define NB        512
#define ND        32
#define NCOND     30
#define NS        21                  // NB_STEPS+1 quadrature nodes
#define NBD       (NB*ND)             // 16384
#define BDPB      3                   // bd-groups per block (63 rows + 1 pad)
#define NBLK      ((NBD + BDPB - 1) / BDPB)   // 5462 blocks

// packed-weight element counts (ushort)
#define W0P_ELEMS (1*16*64*8)         // 8192
#define W1P_ELEMS (8*16*64*8)         // 65536
#define W3P_ELEMS (8*64*8)            // 4096  (zero-padded W3 as A-fragments)
#define WP_TOTAL  (W0P_ELEMS + 2*W1P_ELEMS + W3P_ELEMS)  // 143360

typedef __bf16 bf8 __attribute__((ext_vector_type(8)));
typedef float  fx4 __attribute__((ext_vector_type(4)));
typedef unsigned short us8 __attribute__((ext_vector_type(8)));

__device__ __forceinline__ unsigned short f2bf(float f) {
  unsigned int u = __float_as_uint(f);
  u += 0x7FFFu + ((u >> 16) & 1u);        // round-to-nearest-even
  return (unsigned short)(u >> 16);
}

// ---------------- kernel 1: pack weights + Clenshaw-Curtis weights ----------
__global__ void prep_pack(const float* __restrict__ W0,
                          const float* __restrict__ W1,
                          const float* __restrict__ W2,
                          const float* __restrict__ W3,
                          unsigned short* __restrict__ wp,
                          float* __restrict__ ccwbuf) {
  if (blockIdx.x == 0 && threadIdx.x < NS) {   // cc weights (double prec, once)
    int tid = threadIdx.x;
    double acc = 0.0;
#pragma unroll
    for (int i = 0; i <= 20; i += 2) {
      double wi = (i == 0) ? 1.0 : 2.0 / (1.0 - (double)(i * i));
      acc += cos((double)(i * tid) * 3.141592653589793 / 20.0) * wi;
    }
    double edge = (tid == 0 || tid == 20) ? 0.5 : 1.0;
    ccwbuf[tid] = (float)(acc * 0.1 * edge);
  }
  int t = blockIdx.x * blockDim.x + threadIdx.x;   // one thread = one 8-elem frag
  if (t >= WP_TOTAL / 8) return;
  int base = t * 8;
  us8 out;
  if (base >= W0P_ELEMS + 2 * W1P_ELEMS) {         // W3 region
    int rem  = base - (W0P_ELEMS + 2 * W1P_ELEMS);
    int lane = (rem >> 3) & 63;
    int ktl  = rem >> 9;
    int k0   = ktl * 32 + (lane >> 4) * 8;
#pragma unroll
    for (int i = 0; i < 8; ++i)
      out[i] = ((lane & 15) == 0) ? f2bf(W3[k0 + i]) : (unsigned short)0;
  } else {
    const float* W; int rem, K;
    if (base < W0P_ELEMS)                  { W = W0; rem = base;                 K = 31;  }
    else if (base < W0P_ELEMS + W1P_ELEMS) { W = W1; rem = base - W0P_ELEMS;     K = 256; }
    else                                   { W = W2; rem = base - W0P_ELEMS - W1P_ELEMS; K = 256; }
    int lane = (rem >> 3) & 63;
    int ct   = (rem >> 9) & 15;
    int ktl  =  rem >> 13;
    int j  = ct * 16 + (lane & 15);
    int k0 = ktl * 32 + (lane >> 4) * 8;
#pragma unroll
    for (int i = 0; i < 8; ++i) {
      int k = k0 + i;
      out[i] = (k < K) ? f2bf(W[k * 256 + j]) : (unsigned short)0;
    }
  }
  *reinterpret_cast<us8*>(wp + base) = out;
}

// ---------------- fused MLP + CC-reduction kernel ----------------
// R12 champion structure (4 waves/block, 64 act rows, wave = 4rt x 4ct,
// ping-pong ldsA/ldsB, bias-in-acc, weight+act dbuf, setprio, (256,2)),
// fused output: block owns 3 COMPLETE bd-groups (63 rows, row 63 zero pad;
// rows are GEMM-independent so the pad row contaminates nothing). After L3
// the f values land in ldsF[64]; 3 threads apply cc weights and write z/jac
// directly -> reduce_kernel + fbuf round-trip eliminated.

#define ACC_BIAS(BIAS)                                                           \
  {                                                                              \
    float4 bq0 = *reinterpret_cast<const float4*>((BIAS) + (cgrp * 4 + 0) * 16 + khalf * 4); \
    float4 bq1 = *reinterpret_cast<const float4*>((BIAS) + (cgrp * 4 + 1) * 16 + khalf * 4); \
    float4 bq2 = *reinterpret_cast<const float4*>((BIAS) + (cgrp * 4 + 2) * 16 + khalf * 4); \
    float4 bq3 = *reinterpret_cast<const float4*>((BIAS) + (cgrp * 4 + 3) * 16 + khalf * 4); \
    _Pragma("unroll")                                                            \
    for (int rt = 0; rt < 4; ++rt) {                                             \
      acc[rt][0] = fx4{bq0.x, bq0.y, bq0.z, bq0.w};                              \
      acc[rt][1] = fx4{bq1.x, bq1.y, bq1.z, bq1.w};                              \
      acc[rt][2] = fx4{bq2.x, bq2.y, bq2.z, bq2.w};                              \
      acc[rt][3] = fx4{bq3.x, bq3.y, bq3.z, bq3.w};                              \
    }                                                                            \
  }

#define LOADW4(S0,S1,S2,S3, WB, KT)                                              \
  S0 = *reinterpret_cast<const bf8*>((WB) + (((KT) * 16 + cgrp * 4 + 0) * 64 + lane) * 8); \
  S1 = *reinterpret_cast<const bf8*>((WB) + (((KT) * 16 + cgrp * 4 + 1) * 64 + lane) * 8); \
  S2 = *reinterpret_cast<const bf8*>((WB) + (((KT) * 16 + cgrp * 4 + 2) * 64 + lane) * 8); \
  S3 = *reinterpret_cast<const bf8*>((WB) + (((KT) * 16 + cgrp * 4 + 3) * 64 + lane) * 8);

#define AOFF(M, KT) (((unsigned)((M) * 512 + (KT) * 64 + khalf * 16)) ^ ((unsigned)(((M) & 15) << 4)))

#define KSTEP(SRC, W0_,W1_,W2_,W3_, KT)                                          \
  {                                                                              \
    bf8 a0 = *reinterpret_cast<const bf8*>((SRC) + AOFF( 0 + colb, KT));         \
    bf8 a1 = *reinterpret_cast<const bf8*>((SRC) + AOFF(16 + colb, KT));         \
    bf8 a2 = *reinterpret_cast<const bf8*>((SRC) + AOFF(32 + colb, KT));         \
    bf8 a3 = *reinterpret_cast<const bf8*>((SRC) + AOFF(48 + colb, KT));         \
    __builtin_amdgcn_s_setprio(1);                                               \
    acc[0][0] = __builtin_amdgcn_mfma_f32_16x16x32_bf16(W0_, a0, acc[0][0], 0, 0, 0); \
    acc[0][1] = __builtin_amdgcn_mfma_f32_16x16x32_bf16(W1_, a0, acc[0][1], 0, 0, 0); \
    acc[0][2] = __builtin_amdgcn_mfma_f32_16x16x32_bf16(W2_, a0, acc[0][2], 0, 0, 0); \
    acc[0][3] = __builtin_amdgcn_mfma_f32_16x16x32_bf16(W3_, a0, acc[0][3], 0, 0, 0); \
    acc[1][0] = __builtin_amdgcn_mfma_f32_16x16x32_bf16(W0_, a1, acc[1][0], 0, 0, 0); \
    acc[1][1] = __builtin_amdgcn_mfma_f32_16x16x32_bf16(W1_, a1, acc[1][1], 0, 0, 0); \
    acc[1][2] = __builtin_amdgcn_mfma_f32_16x16x32_bf16(W2_, a1, acc[1][2], 0, 0, 0); \
    acc[1][3] = __builtin_amdgcn_mfma_f32_16x16x32_bf16(W3_, a1, acc[1][3], 0, 0, 0); \
    acc[2][0] = __builtin_amdgcn_mfma_f32_16x16x32_bf16(W0_, a2, acc[2][0], 0, 0, 0); \
    acc[2][1] = __builtin_amdgcn_mfma_f32_16x16x32_bf16(W1_, a2, acc[2][1], 0, 0, 0); \
    acc[2][2] = __builtin_amdgcn_mfma_f32_16x16x32_bf16(W2_, a2, acc[2][2], 0, 0, 0); \
    acc[2][3] = __builtin_amdgcn_mfma_f32_16x16x32_bf16(W3_, a2, acc[2][3], 0, 0, 0); \
    acc[3][0] = __builtin_amdgcn_mfma_f32_16x16x32_bf16(W0_, a3, acc[3][0], 0, 0, 0); \
    acc[3][1] = __builtin_amdgcn_mfma_f32_16x16x32_bf16(W1_, a3, acc[3][1], 0, 0, 0); \
    acc[3][2] = __builtin_amdgcn_mfma_f32_16x16x32_bf16(W2_, a3, acc[3][2], 0, 0, 0); \
    acc[3][3] = __builtin_amdgcn_mfma_f32_16x16x32_bf16(W3_, a3, acc[3][3], 0, 0, 0); \
    __builtin_amdgcn_s_setprio(0);                                               \
  }

// K-steps 0..7, consuming alternating slots, prefetching kt+2 (then next layer)
#define DENSE_PIPE(SRC, WB, NWB)                                                 \
  KSTEP(SRC, wa0,wa1,wa2,wa3, 0) LOADW4(wa0,wa1,wa2,wa3, WB, 2)                  \
  KSTEP(SRC, wb0,wb1,wb2,wb3, 1) LOADW4(wb0,wb1,wb2,wb3, WB, 3)                  \
  KSTEP(SRC, wa0,wa1,wa2,wa3, 2) LOADW4(wa0,wa1,wa2,wa3, WB, 4)                  \
  KSTEP(SRC, wb0,wb1,wb2,wb3, 3) LOADW4(wb0,wb1,wb2,wb3, WB, 5)                  \
  KSTEP(SRC, wa0,wa1,wa2,wa3, 4) LOADW4(wa0,wa1,wa2,wa3, WB, 6)                  \
  KSTEP(SRC, wb0,wb1,wb2,wb3, 5) LOADW4(wb0,wb1,wb2,wb3, WB, 7)                  \
  KSTEP(SRC, wa0,wa1,wa2,wa3, 6) LOADW4(wa0,wa1,wa2,wa3, NWB, 0)                 \
  KSTEP(SRC, wb0,wb1,wb2,wb3, 7) LOADW4(wb0,wb1,wb2,wb3, NWB, 1)

#define DENSE_LAST(SRC, WB)                                                      \
  KSTEP(SRC, wa0,wa1,wa2,wa3, 0) LOADW4(wa0,wa1,wa2,wa3, WB, 2)                  \
  KSTEP(SRC, wb0,wb1,wb2,wb3, 1) LOADW4(wb0,wb1,wb2,wb3, WB, 3)                  \
  KSTEP(SRC, wa0,wa1,wa2,wa3, 2) LOADW4(wa0,wa1,wa2,wa3, WB, 4)                  \
  KSTEP(SRC, wb0,wb1,wb2,wb3, 3) LOADW4(wb0,wb1,wb2,wb3, WB, 5)                  \
  KSTEP(SRC, wa0,wa1,wa2,wa3, 4) LOADW4(wa0,wa1,wa2,wa3, WB, 6)                  \
  KSTEP(SRC, wb0,wb1,wb2,wb3, 5) LOADW4(wb0,wb1,wb2,wb3, WB, 7)                  \
  KSTEP(SRC, wa0,wa1,wa2,wa3, 6)                                                 \
  KSTEP(SRC, wb0,wb1,wb2,wb3, 7)

// ReLU + bf16-pack + ds_write_b64 store of acc into DST (bias already in acc)
#define ACT_STORE(DST)                                                           \
  {                                                                              \
    _Pragma("unroll")                                                            \
    for (int rt = 0; rt < 4; ++rt) {                                             \
      int m = rt * 16 + colb;                                                    \
      unsigned int sbase = (unsigned int)(m * 512);                              \
      unsigned int swz   = (unsigned int)((m & 15) << 4);                        \
      _Pragma("unroll")                                                          \
      for (int ct = 0; ct < 4; ++ct) {                                           \
        int n0 = (cgrp * 4 + ct) * 16 + khalf * 4;                               \
        float v0 = fmaxf(acc[rt][ct][0], 0.f);                                   \
        float v1 = fmaxf(acc[rt][ct][1], 0.f);                                   \
        float v2 = fmaxf(acc[rt][ct][2], 0.f);                                   \
        float v3 = fmaxf(acc[rt][ct][3], 0.f);                                   \
        unsigned int p0, p1;                                                     \
        asm("v_cvt_pk_bf16_f32 %0, %1, %2" : "=v"(p0) : "v"(v0), "v"(v1));       \
        asm("v_cvt_pk_bf16_f32 %0, %1, %2" : "=v"(p1) : "v"(v2), "v"(v3));       \
        uint2 pk; pk.x = p0; pk.y = p1;                                          \
        *reinterpret_cast<uint2*>((DST) + ((sbase + (unsigned int)(n0 * 2)) ^ swz)) = pk; \
      }                                                                          \
    }                                                                            \
  }

__global__ __launch_bounds__(256, 2)
void mlp_kernel(const float* __restrict__ x, const float* __restrict__ h,
                const float* __restrict__ b0, const float* __restrict__ b1,
                const float* __restrict__ b2, const float* __restrict__ b3,
                const unsigned short* __restrict__ wp,
                const float* __restrict__ ccw,
                float* __restrict__ out) {
  __shared__ __align__(16) unsigned char ldsA[64 * 512];     // 32 KiB
  __shared__ __align__(16) unsigned char ldsB[64 * 512];     // 32 KiB
  __shared__ float ldsF[64];
  unsigned char* ldsIn = ldsB;         // layer-0 input overlays ldsB[0:4K]

  int tid  = threadIdx.x;
  int wv   = tid >> 6;
  int lane = tid & 63;
  int cgrp = wv;                 // 0..3 : 64-neuron group; wave owns all 64 rows
  int colb  = lane & 15;
  int khalf = lane >> 4;
  int blkbd = blockIdx.x * BDPB;

  const unsigned short* wb1p = wp + W0P_ELEMS;
  const unsigned short* wb2p = wp + W0P_ELEMS + W1P_ELEMS;
  const unsigned short* w3p  = wp + W0P_ELEMS + 2 * W1P_ELEMS;

  bf8 wa0, wa1, wa2, wa3, wb0, wb1, wb2, wb3;
  // layer-0 weights (single K-step) into slot A, issued before input staging
  LOADW4(wa0, wa1, wa2, wa3, wp, 0);

  // ---- stage layer-0 input: 63 real rows (3 bd x 21 s) + 1 zero pad row ----
  {
    int r = tid >> 2;                   // 0..63 (row within block)
    int q = tid & 3;                    // 8-col chunk
    unsigned int u = (unsigned int)r / NS;       // 0..2 (r=63 -> u=3)
    int s = r - (int)u * NS;
    int bd = blkbd + (int)u;
    us8 au = us8{0,0,0,0,0,0,0,0};
    if (r < 63 && bd < NBD) {
      float xv = x[bd];
      float node = xv * (cosf((float)s * 0.15707963267948966f) + 1.0f) * 0.5f;
      const float* hrow = h + bd * NCOND;
#pragma unroll
      for (int i = 0; i < 8; ++i) {
        int c = q * 8 + i;
        float v;
        if (c == 0)       v = node;
        else if (c <= 30) v = hrow[c - 1];
        else              v = 0.0f;
        au[i] = f2bf(v);
      }
    }
    unsigned int off = (unsigned int)(r * 64 + q * 16) ^ (unsigned int)((r & 3) << 4);
    *reinterpret_cast<us8*>(ldsIn + off) = au;
  }
  __syncthreads();

  fx4 acc[4][4];

  // ======== layer 0: K=32, read ldsIn(B), store ldsA — no mid barrier ========
  {
    ACC_BIAS(b0);
#pragma unroll
    for (int rt = 0; rt < 4; ++rt) {
      int m = rt * 16 + colb;
      unsigned int off = (unsigned int)(m * 64 + khalf * 16) ^ (unsigned int)((m & 3) << 4);
      bf8 a = *reinterpret_cast<const bf8*>(ldsIn + off);
      acc[rt][0] = __builtin_amdgcn_mfma_f32_16x16x32_bf16(wa0, a, acc[rt][0], 0, 0, 0);
      acc[rt][1] = __builtin_amdgcn_mfma_f32_16x16x32_bf16(wa1, a, acc[rt][1], 0, 0, 0);
      acc[rt][2] = __builtin_amdgcn_mfma_f32_16x16x32_bf16(wa2, a, acc[rt][2], 0, 0, 0);
      acc[rt][3] = __builtin_amdgcn_mfma_f32_16x16x32_bf16(wa3, a, acc[rt][3], 0, 0, 0);
    }
    // prefetch layer-1 kt0/kt1; loads straddle the store + barrier
    LOADW4(wa0, wa1, wa2, wa3, wb1p, 0);
    LOADW4(wb0, wb1, wb2, wb3, wb1p, 1);
    ACT_STORE(ldsA);                    // different buffer: no barrier needed
  }
  __syncthreads();

  // ======== layer 1: read ldsA, store ldsB (one barrier after stores) ========
  ACC_BIAS(b1);
  DENSE_PIPE(ldsA, wb1p, wb2p);          // tail prefetches layer-2 kt0/kt1
  ACT_STORE(ldsB);
  __syncthreads();

  // ======== layer 2: read ldsB, store ldsA ========
  ACC_BIAS(b2);
  DENSE_LAST(ldsB, wb2p);
  ACT_STORE(ldsA);
  __syncthreads();

  // ======== layer 3: 256 -> 1 via MFMA, wave wv handles rows wv*16..wv*16+15 ==
  {
    fx4 a3 = fx4{0.f, 0.f, 0.f, 0.f};
    int m = wv * 16 + colb;
    unsigned int abase = (unsigned int)(m * 512 + khalf * 16);
    unsigned int aswz  = (unsigned int)((m & 15) << 4);
#pragma unroll
    for (int kt = 0; kt < 8; ++kt) {
      bf8 w3f = *reinterpret_cast<const bf8*>(w3p + (kt * 64 + lane) * 8);
      bf8 a = *reinterpret_cast<const bf8*>(ldsA + ((abase + (unsigned)(kt * 64)) ^ aswz));
      a3 = __builtin_amdgcn_mfma_f32_16x16x32_bf16(w3f, a, a3, 0, 0, 0);
    }
    if (lane < 16) {
      float y = a3[0] + b3[0];
      float f = (y > 0.f) ? (y + 1.f) : expf(y);   // elu(y)+1
      ldsF[wv * 16 + lane] = f;
    }
  }
  __syncthreads();

  // ======== fused Clenshaw-Curtis reduction: 3 threads, one bd each ========
  if (tid < BDPB) {
    int bd = blkbd + tid;
    if (bd < NBD) {
      float acc2 = 0.f;
#pragma unroll
      for (int s2 = 0; s2 < NS; ++s2) acc2 += ldsF[tid * NS + s2] * ccw[s2];
      out[bd] = acc2 * x[bd] * 0.5f + h[bd * NCOND];  // z = z_est + h[:,:,0]
      out[NBD + bd] = ldsF[tid * NS];                 // jac = f at s=0
    }
  }
}

// ---------------- launcher ----------------
extern "C" void kernel_launch(void* const* d_in, const int* in_sizes, int n_in,
                              void* d_out, int out_size, void* d_ws, size_t ws_size,
                              hipStream_t stream) {
  (void)in_sizes; (void)n_in; (void)out_size; (void)ws_size;
  const float* x  = (const float*)d_in[0];
  const float* h  = (const float*)d_in[1];
  const float* W0 = (const float*)d_in[2];
  const float* b0 = (const float*)d_in[3];
  const float* W1 = (const float*)d_in[4];
  const float* b1 = (const float*)d_in[5];
  const float* W2 = (const float*)d_in[6];
  const float* b2 = (const float*)d_in[7];
  const float* W3 = (const float*)d_in[8];
  const float* b3 = (const float*)d_in[9];

  unsigned short* wp = (unsigned short*)d_ws;
  float* ccwbuf = (float*)((char*)d_ws + WP_TOTAL * sizeof(unsigned short));
  float* out  = (float*)d_out;

  prep_pack<<<(WP_TOTAL / 8 + 255) / 256, 256, 0, stream>>>(W0, W1, W2, W3, wp, ccwbuf);
  mlp_kernel<<<NBLK, 256, 0, stream>>>(x, h, b0, b1, b2, b3, wp, ccwbuf, out);
}